// Round 19
// baseline (2294.918 us; speedup 1.0000x reference)
//
#include <hip/hip_runtime.h>
#include <hip/hip_bf16.h>

typedef __attribute__((ext_vector_type(8))) short bf16x8;
typedef __attribute__((ext_vector_type(4))) float f32x4;
typedef __attribute__((ext_vector_type(2))) unsigned int u32x2;
typedef unsigned short u16;
typedef unsigned int u32;

__device__ __forceinline__ u16 f2bf(float f) {
  union { float f; unsigned u; } v; v.f = f;
  unsigned r = v.u + 0x7FFFu + ((v.u >> 16) & 1u);   // RTNE
  return (u16)(r >> 16);
}

__device__ __forceinline__ float sigm_fast(float x) {
  return __builtin_amdgcn_rcpf(1.f + __expf(-x));
}
__device__ __forceinline__ float tanh_fast(float x) {
  x = fminf(fmaxf(x, -15.f), 15.f);
  float e = __expf(2.f * x);
  return (e - 1.f) * __builtin_amdgcn_rcpf(e + 1.f);
}

// ---- untracked (inline-asm) memory ops: caller owns the vmcnt ledger ----
__device__ __forceinline__ void ld_llc_b128(const u16* p, bf16x8& r) {  // coherent
  asm volatile("global_load_dwordx4 %0, %1, off sc0 sc1" : "=&v"(r) : "v"(p));
}
__device__ __forceinline__ void ld_g_b128(const u16* p, bf16x8& r) {    // cached
  asm volatile("global_load_dwordx4 %0, %1, off" : "=&v"(r) : "v"(p));
}
__device__ __forceinline__ void st_llc_b64(u16* p, u32x2 v) {           // coherent
  asm volatile("global_store_dwordx2 %0, %1, off sc0 sc1" :: "v"(p), "v"(v) : "memory");
}
__device__ __forceinline__ void st_g_b32(u32* p, u32 v) {               // cached
  asm volatile("global_store_dword %0, %1, off" :: "v"(p), "v"(v) : "memory");
}

// ---------------------------------------------------------------------------
// fold (all 4 gates, z = gate): Wt[(j*4+g)][k] = sum_m P[m][j]*(W[k][m]*cos(rx[m]))
// ---------------------------------------------------------------------------
__global__ __launch_bounds__(256) void fold_kernel(
    const float* __restrict__ W0, const float* __restrict__ rx0, const float* __restrict__ P0,
    const float* __restrict__ W1, const float* __restrict__ rx1, const float* __restrict__ P1,
    const float* __restrict__ W2, const float* __restrict__ rx2, const float* __restrict__ P2,
    const float* __restrict__ W3, const float* __restrict__ rx3, const float* __restrict__ P3,
    u16* __restrict__ Wt)
{
  const int g = blockIdx.z;
  const float* W  = (g == 0) ? W0  : (g == 1) ? W1  : (g == 2) ? W2  : W3;
  const float* rx = (g == 0) ? rx0 : (g == 1) ? rx1 : (g == 2) ? rx2 : rx3;
  const float* P  = (g == 0) ? P0  : (g == 1) ? P1  : (g == 2) ? P2  : P3;
  __shared__ __align__(16) float As[16][68];
  __shared__ __align__(16) float Bs[16][68];
  const int bk = blockIdx.x, bj = blockIdx.y;
  const int tid = threadIdx.x;
  const int tx = tid & 15, ty = tid >> 4;
  const int j0 = bj * 64, k0 = bk * 64;
  float acc[4][4] = {};
  for (int m0 = 0; m0 < 512; m0 += 16) {
#pragma unroll
    for (int l = 0; l < 4; ++l) {
      int lin = tid + 256 * l;
      int mm = lin >> 6, jr = lin & 63;
      As[mm][jr] = P[(m0 + mm) * 512 + j0 + jr];
      int kk = lin >> 4, mb = lin & 15;
      Bs[mb][kk] = W[(k0 + kk) * 512 + m0 + mb] * cosf(rx[m0 + mb]);
    }
    __syncthreads();
#pragma unroll
    for (int mm = 0; mm < 16; ++mm) {
      f32x4 a = *(const f32x4*)&As[mm][ty * 4];
      f32x4 b = *(const f32x4*)&Bs[mm][tx * 4];
#pragma unroll
      for (int i = 0; i < 4; ++i)
#pragma unroll
        for (int jj = 0; jj < 4; ++jj)
          acc[i][jj] += a[i] * b[jj];
    }
    __syncthreads();
  }
#pragma unroll
  for (int i = 0; i < 4; ++i) {
    int j = j0 + ty * 4 + i;
    size_t n = (size_t)(j * 4 + g);
    ushort4 w;
    w.x = f2bf(acc[i][0]); w.y = f2bf(acc[i][1]);
    w.z = f2bf(acc[i][2]); w.w = f2bf(acc[i][3]);
    *(ushort4*)(Wt + n * 1024 + k0 + tx * 4) = w;
  }
}

// bpn[j*4+g]; grid 32 = 4 gates x 8 j-blocks
__global__ __launch_bounds__(256) void fold_bias(
    const float* __restrict__ b0, const float* __restrict__ rx0, const float* __restrict__ P0,
    const float* __restrict__ b1, const float* __restrict__ rx1, const float* __restrict__ P1,
    const float* __restrict__ b2, const float* __restrict__ rx2, const float* __restrict__ P2,
    const float* __restrict__ b3, const float* __restrict__ rx3, const float* __restrict__ P3,
    float* __restrict__ bpn)
{
  const int g = blockIdx.x >> 3, jb = blockIdx.x & 7;
  const float* b  = (g == 0) ? b0  : (g == 1) ? b1  : (g == 2) ? b2  : b3;
  const float* rx = (g == 0) ? rx0 : (g == 1) ? rx1 : (g == 2) ? rx2 : rx3;
  const float* P  = (g == 0) ? P0  : (g == 1) ? P1  : (g == 2) ? P2  : P3;
  __shared__ float bc[512];
  __shared__ float red[4][65];
  const int tid = threadIdx.x;
  bc[tid] = b[tid] * cosf(rx[tid]);
  bc[tid + 256] = b[tid + 256] * cosf(rx[tid + 256]);
  __syncthreads();
  const int jl = tid & 63, msub = tid >> 6;
  const int j = jb * 64 + jl;
  float acc = 0.f;
  for (int m = msub * 128; m < msub * 128 + 128; ++m)
    acc += bc[m] * P[m * 512 + j];
  red[msub][jl] = acc;
  __syncthreads();
  if (msub == 0)
    bpn[j * 4 + g] = red[0][jl] + red[1][jl] + red[2][jl] + red[3][jl];
}

__global__ __launch_bounds__(256) void xcvt_kernel(
    const float* __restrict__ x, u16* __restrict__ xb)
{
  size_t i = (size_t)blockIdx.x * 256 + threadIdx.x;
  f32x4 v = *(const f32x4*)(x + i * 4);
  ushort4 w;
  w.x = f2bf(v[0]); w.y = f2bf(v[1]); w.z = f2bf(v[2]); w.w = f2bf(v[3]);
  *(ushort4*)(xb + i * 4) = w;
}

// zero hbuf (both parities) + cbuf + flags, every launch (replay determinism)
__global__ __launch_bounds__(256) void init_kernel(u32* hbuf32, float* cbuf,
                                                   u32* flags) {
  int i = blockIdx.x * 256 + threadIdx.x;      // 65536
  hbuf32[i] = 0;
  cbuf[i] = 0.f;
  if (i < 1024) flags[i] = 0;
}

__global__ __launch_bounds__(256) void tail_kernel(
    const float* __restrict__ hlast, const float* __restrict__ c,
    float* __restrict__ hx, float* __restrict__ cx)
{
  int i = blockIdx.x * 256 + threadIdx.x;
  hx[i] = hlast[i];
  cx[i] = c[i];
}

// ---------------------------------------------------------------------------
// fallback single-step kernel (R1-proven)
// ---------------------------------------------------------------------------
__global__ __launch_bounds__(256) void step_kernel(
    const u16* __restrict__ xb_t, const u16* __restrict__ h_in,
    u16* __restrict__ h_out, const u16* __restrict__ Wt,
    const float* __restrict__ bpn, float* __restrict__ cbuf,
    float* __restrict__ out_t)
{
  __shared__ float pre_s[32][33];
  const int bid = blockIdx.x;
  const int mb = bid >> 6, nb = bid & 63;
  const int b0 = mb * 32, n0 = nb * 32;
  const int tid = threadIdx.x;
  const int wv = tid >> 6, lane = tid & 63;
  const int rt = wv >> 1, nt = wv & 1;
  const int l15 = lane & 15, kg = lane >> 4;
  const int brow = b0 + rt * 16 + l15;
  const int ncol = n0 + nt * 16 + l15;
  const u16* wrow = Wt + (size_t)ncol * 1024;
  const u16* xrow = xb_t + (size_t)brow * 512;
  const u16* hrow = h_in + (size_t)brow * 512;
  f32x4 acc = {0.f, 0.f, 0.f, 0.f};
#pragma unroll 8
  for (int kk = 0; kk < 32; ++kk) {
    const int kb = kk * 32 + kg * 8;
    bf16x8 bfrag = *(const bf16x8*)(wrow + kb);
    bf16x8 afrag;
    if (kb < 512) afrag = *(const bf16x8*)(xrow + kb);
    else          afrag = *(const bf16x8*)(hrow + (kb - 512));
    acc = __builtin_amdgcn_mfma_f32_16x16x32_bf16(afrag, bfrag, acc, 0, 0, 0);
  }
  const float bias = bpn[ncol];
#pragma unroll
  for (int q = 0; q < 4; ++q)
    pre_s[rt * 16 + kg * 4 + q][nt * 16 + l15] = acc[q] + bias;
  __syncthreads();
  const int bb = tid >> 3, jo = tid & 7;
  float pf = pre_s[bb][jo * 4 + 0];
  float pi = pre_s[bb][jo * 4 + 1];
  float pu = pre_s[bb][jo * 4 + 2];
  float po = pre_s[bb][jo * 4 + 3];
  float fg = 1.f / (1.f + __expf(-pf));
  float ig = 1.f / (1.f + __expf(-pi));
  float gg = tanhf(pu);
  float og = 1.f / (1.f + __expf(-po));
  size_t idx = (size_t)(b0 + bb) * 512 + (size_t)(nb * 8 + jo);
  float cv = fg * cbuf[idx] + ig * gg;
  cbuf[idx] = cv;
  float hv = og * tanhf(cv);
  out_t[idx] = hv;
  h_out[idx] = f2bf(hv);
}

// ---------------------------------------------------------------------------
// persistent recurrence v13: WAVE-AUTONOMOUS, zero barriers, per-wave flags.
// 8 row-groups x 16 rows; 32 wgs/group; wave owns a 16x16 tile whose 16
// gate-cols = 4 complete h-cols x 4 gates -> transpose + cell update are
// intra-wave (per-wave LDS patch, lgkmcnt only; R14-proven). Each wave polls
// the 128 group wave-flags itself (2/lane), loads h once, computes, stores
// packed 8B h-rows, drains, sets ITS OWN flag. No s_barrier anywhere in the
// loop. 2-buffer safety: flag(t+1) implies that wave's buf[t&1] reads done.
// ---------------------------------------------------------------------------
__global__ __launch_bounds__(256, 1) void qlstm_persistent(
    const u16* __restrict__ Xbf,    // [256][128][512] bf16
    u16* __restrict__ hbuf,         // [2][128][512] bf16
    const u16* __restrict__ Wt,     // [2048][1024] bf16, n = j*4+g
    const float* __restrict__ bpn,  // [2048] f32
    float* __restrict__ out,        // [256][128][512] + hx + cx
    u32* __restrict__ flags)        // [1024] = wg*4 + wave
{
  __shared__ float pre_s[4][16][17];
  const int bid = blockIdx.x;
  const int g  = bid & 7;            // row-group (rows g*16..g*16+15)
  const int nb = bid >> 3;           // 0..31 col-slice (64 gate cols)
  const int b0 = g * 16;
  const int tid = threadIdx.x;
  const int wv = tid >> 6, lane = tid & 63;
  const int l15 = lane & 15, kg = lane >> 4;
  const int brow = b0 + l15;                    // A-frag / h row
  const int ncol = nb * 64 + wv * 16 + l15;     // gate col

  // W fragments, both halves (128 VGPR)
  const u16* wrow = Wt + (size_t)ncol * 1024;
  bf16x8 warr[32];
#pragma unroll
  for (int kk = 0; kk < 32; ++kk)
    warr[kk] = *(const bf16x8*)(wrow + kk * 32 + kg * 8);
  const float bnc = bpn[ncol];

  // cell mapping: lane -> (row = l15, h-col = jglob)
  const int jglob = nb * 16 + wv * 4 + kg;
  const size_t eidx = (size_t)brow * 512 + (size_t)jglob;
  const size_t hrow_off = (size_t)brow * 512 + (size_t)(nb * 16 + wv * 4);
  // per-lane two poll indices covering the group's 32 wgs x 4 waves
  const int fi1 = 4 * g + 32 * (lane >> 2) + (lane & 3);
  const int fi2 = fi1 + 512;
  float cst = 0.f, hl = 0.f;

  // prologue: x-loads for t=0
  bf16x8 xf[16];
  {
    const u16* xr = Xbf + (size_t)brow * 512;
#pragma unroll
    for (int kk = 0; kk < 16; ++kk)
      ld_g_b128(xr + kk * 32 + kg * 8, xf[kk]);
    asm volatile("s_waitcnt vmcnt(0)" ::: "memory");
  }

  for (int t = 0; t < 256; ++t) {
    // ---- per-wave poll: all 128 group wave-flags >= t (busy spin) ----
    if (t > 0) {
      int guard = 0;
      for (;;) {
        u32 f1 = __hip_atomic_load(&flags[fi1], __ATOMIC_RELAXED,
                                   __HIP_MEMORY_SCOPE_AGENT);
        u32 f2 = __hip_atomic_load(&flags[fi2], __ATOMIC_RELAXED,
                                   __HIP_MEMORY_SCOPE_AGENT);
        if (__all((int)(f1 >= (u32)t && f2 >= (u32)t))) break;
        if (++guard > 2000000) break;        // bounded: fail loudly, no hang
      }
      asm volatile("" ::: "memory");
    }

    // ---- issue coherent h-loads (x already drained during poll) ----
    bf16x8 hf[16];
    if (t > 0) {
      const u16* hr = hbuf + (size_t)((t & 1) ? 65536 : 0) + (size_t)brow * 512;
#pragma unroll
      for (int kk = 0; kk < 16; ++kk)
        ld_llc_b128(hr + kk * 32 + kg * 8, hf[kk]);
    }

    // ---- x-MFMAs from registers (overlap h-load flight) ----
    f32x4 ax0 = {0,0,0,0}, ax1 = {0,0,0,0};
#pragma unroll
    for (int kk = 0; kk < 16; kk += 2) {
      ax0 = __builtin_amdgcn_mfma_f32_16x16x32_bf16(xf[kk],     warr[kk],     ax0, 0, 0, 0);
      ax1 = __builtin_amdgcn_mfma_f32_16x16x32_bf16(xf[kk + 1], warr[kk + 1], ax1, 0, 0, 0);
    }

    // ---- h-MFMAs after drain ----
    f32x4 ah0 = {0,0,0,0}, ah1 = {0,0,0,0};
    if (t > 0) {
      asm volatile("s_waitcnt vmcnt(0)" ::: "memory");
      __builtin_amdgcn_sched_barrier(0);
#pragma unroll
      for (int kk = 0; kk < 16; kk += 2) {
        ah0 = __builtin_amdgcn_mfma_f32_16x16x32_bf16(hf[kk],     warr[16 + kk],     ah0, 0, 0, 0);
        ah1 = __builtin_amdgcn_mfma_f32_16x16x32_bf16(hf[kk + 1], warr[16 + kk + 1], ah1, 0, 0, 0);
      }
    }
    f32x4 acc = (ax0 + ax1) + (ah0 + ah1);

    // ---- intra-wave gate transpose (own LDS patch; lgkmcnt only) ----
    // C/D layout: col = l15, row = kg*4+q
#pragma unroll
    for (int q = 0; q < 4; ++q)
      pre_s[wv][kg * 4 + q][l15] = acc[q] + bnc;
    asm volatile("s_waitcnt lgkmcnt(0)" ::: "memory");
    __builtin_amdgcn_sched_barrier(0);
    f32x4 g4 = *(const f32x4*)&pre_s[wv][l15][kg * 4];
    asm volatile("s_waitcnt lgkmcnt(0)" ::: "memory");
    __builtin_amdgcn_sched_barrier(0);

    // ---- gates + cell update: lane owns (row=l15, col=jglob) ----
    cst = sigm_fast(g4[0]) * cst + sigm_fast(g4[1]) * tanh_fast(g4[2]);
    float hv = sigm_fast(g4[3]) * tanh_fast(cst);
    hl = hv;

    // ---- packed coherent h-store: 4 cols of this row -> one dwordx2 ----
    u16 myh = f2bf(hv);
    u32 w  = (u32)myh | ((u32)(u16)__shfl_xor((int)(u32)myh, 16) << 16);
    u32 w2 = (u32)__shfl_xor((int)w, 32);
    u16* hnext = hbuf + (size_t)(((t + 1) & 1) ? 65536 : 0);
    if (kg == 0) {
      u32x2 hw = {w, w2};
      st_llc_b64(hnext + hrow_off, hw);
    }
    asm volatile("s_waitcnt vmcnt(0)" ::: "memory");   // h-store drained

    // ---- per-wave flag release (atomic path, immediate visibility) ----
    if (lane == 0)
      (void)__hip_atomic_exchange(&flags[bid * 4 + wv], (u32)(t + 1),
                                  __ATOMIC_RELAXED, __HIP_MEMORY_SCOPE_AGENT);

    // ---- post-flag: out-store + x prefetch for t+1 (fire-and-forget) ----
    union { float f; u32 u; } ho; ho.f = hv;
    st_g_b32((u32*)(out + (size_t)t * 65536 + eidx), ho.u);
    if (t < 255) {
      const u16* xr = Xbf + (size_t)(t + 1) * 65536 + (size_t)brow * 512;
#pragma unroll
      for (int kk = 0; kk < 16; ++kk)
        ld_g_b128(xr + kk * 32 + kg * 8, xf[kk]);
    }
  }

  asm volatile("s_waitcnt vmcnt(0)" ::: "memory");
  out[(size_t)256 * 65536 + eidx] = hl;
  out[(size_t)256 * 65536 + 65536 + eidx] = cst;
}

// ---------------------------------------------------------------------------
extern "C" void kernel_launch(void* const* d_in, const int* in_sizes, int n_in,
                              void* d_out, int out_size, void* d_ws, size_t ws_size,
                              hipStream_t stream) {
  (void)in_sizes; (void)n_in; (void)out_size; (void)ws_size;
  const float* inp = (const float*)d_in[0];
  float* out = (float*)d_out;

  // ws: Xbf 33554432 | Wt 4194304 | bpn 8192 | hbuf 262144 | flags 4096 | cbuf 262144
  char* base = (char*)d_ws;
  u16*   Xbf   = (u16*)base;
  u16*   Wt    = (u16*)(base + 33554432);
  float* bpn   = (float*)(base + 33554432 + 4194304);
  u16*   hbuf  = (u16*)(base + 33554432 + 4194304 + 8192);
  u32*   flags = (u32*)(base + 33554432 + 4194304 + 8192 + 262144);
  float* cbuf  = (float*)(base + 33554432 + 4194304 + 8192 + 262144 + 4096);

  const float* W[4];  const float* b[4];  const float* rx[4];  const float* P[4];
  for (int g = 0; g < 4; ++g) {
    W[g]  = (const float*)d_in[1 + 4 * g];
    b[g]  = (const float*)d_in[2 + 4 * g];
    rx[g] = (const float*)d_in[3 + 4 * g];
    P[g]  = (const float*)d_in[4 + 4 * g];
  }
  fold_kernel<<<dim3(16, 8, 4), 256, 0, stream>>>(
      W[0], rx[0], P[0], W[1], rx[1], P[1],
      W[2], rx[2], P[2], W[3], rx[3], P[3], Wt);
  fold_bias<<<dim3(32), 256, 0, stream>>>(
      b[0], rx[0], P[0], b[1], rx[1], P[1],
      b[2], rx[2], P[2], b[3], rx[3], P[3], bpn);
  xcvt_kernel<<<16384, 256, 0, stream>>>(inp, Xbf);
  init_kernel<<<256, 256, 0, stream>>>((u32*)hbuf, cbuf, flags);

  void* args[6];
  const u16* Xbf_c = Xbf;
  const u16* Wt_c = Wt;
  const float* bpn_c = bpn;
  u16* hbuf_p = hbuf;
  float* out_p = out;
  u32* flags_p = flags;
  args[0] = (void*)&Xbf_c;
  args[1] = (void*)&hbuf_p;
  args[2] = (void*)&Wt_c;
  args[3] = (void*)&bpn_c;
  args[4] = (void*)&out_p;
  args[5] = (void*)&flags_p;
  hipError_t e = hipLaunchCooperativeKernel((const void*)qlstm_persistent,
                                            dim3(256), dim3(256), args, 0, stream);
  if (e != hipSuccess) {
    for (int t = 0; t < 256; ++t) {
      const u16* xb_t  = Xbf + (size_t)t * 65536;
      const u16* h_in  = hbuf + (size_t)(t & 1) * 65536;
      u16*       h_oup = hbuf + (size_t)((t & 1) ^ 1) * 65536;
      float*     out_t = out + (size_t)t * 65536;
      step_kernel<<<256, 256, 0, stream>>>(xb_t, h_in, h_oup, Wt, bpn, cbuf, out_t);
    }
    tail_kernel<<<256, 256, 0, stream>>>(out + (size_t)255 * 65536, cbuf,
                                         out + (size_t)256 * 65536,
                                         out + (size_t)256 * 65536 + 65536);
  }
}

// Round 20
// 1363.559 us; speedup vs baseline: 1.6830x; 1.6830x over previous
//
#include <hip/hip_runtime.h>
#include <hip/hip_bf16.h>

typedef __attribute__((ext_vector_type(8))) short bf16x8;
typedef __attribute__((ext_vector_type(4))) float f32x4;
typedef __attribute__((ext_vector_type(2))) unsigned int u32x2;
typedef unsigned short u16;
typedef unsigned int u32;

__device__ __forceinline__ u16 f2bf(float f) {
  union { float f; unsigned u; } v; v.f = f;
  unsigned r = v.u + 0x7FFFu + ((v.u >> 16) & 1u);   // RTNE
  return (u16)(r >> 16);
}

__device__ __forceinline__ float sigm_fast(float x) {
  return __builtin_amdgcn_rcpf(1.f + __expf(-x));
}
__device__ __forceinline__ float tanh_fast(float x) {
  x = fminf(fmaxf(x, -15.f), 15.f);
  float e = __expf(2.f * x);
  return (e - 1.f) * __builtin_amdgcn_rcpf(e + 1.f);
}

// ---- untracked (inline-asm) memory ops: caller owns the vmcnt ledger ----
__device__ __forceinline__ void ld_llc_b128(const u16* p, bf16x8& r) {  // coherent
  asm volatile("global_load_dwordx4 %0, %1, off sc0 sc1" : "=&v"(r) : "v"(p));
}
__device__ __forceinline__ void ld_g_b128(const u16* p, bf16x8& r) {    // cached
  asm volatile("global_load_dwordx4 %0, %1, off" : "=&v"(r) : "v"(p));
}
__device__ __forceinline__ void st_llc_b64(u16* p, u32x2 v) {           // coherent
  asm volatile("global_store_dwordx2 %0, %1, off sc0 sc1" :: "v"(p), "v"(v) : "memory");
}
__device__ __forceinline__ void st_g_b32(u32* p, u32 v) {               // cached
  asm volatile("global_store_dword %0, %1, off" :: "v"(p), "v"(v) : "memory");
}
__device__ __forceinline__ void at_swap(u32* p, u32 v) {                // untracked
  asm volatile("global_atomic_swap %0, %1, off" :: "v"(p), "v"(v) : "memory");
}

// ---------------------------------------------------------------------------
// fold (all 4 gates, z = gate): Wt[(j*4+g)][k] = sum_m P[m][j]*(W[k][m]*cos(rx[m]))
// ---------------------------------------------------------------------------
__global__ __launch_bounds__(256) void fold_kernel(
    const float* __restrict__ W0, const float* __restrict__ rx0, const float* __restrict__ P0,
    const float* __restrict__ W1, const float* __restrict__ rx1, const float* __restrict__ P1,
    const float* __restrict__ W2, const float* __restrict__ rx2, const float* __restrict__ P2,
    const float* __restrict__ W3, const float* __restrict__ rx3, const float* __restrict__ P3,
    u16* __restrict__ Wt)
{
  const int g = blockIdx.z;
  const float* W  = (g == 0) ? W0  : (g == 1) ? W1  : (g == 2) ? W2  : W3;
  const float* rx = (g == 0) ? rx0 : (g == 1) ? rx1 : (g == 2) ? rx2 : rx3;
  const float* P  = (g == 0) ? P0  : (g == 1) ? P1  : (g == 2) ? P2  : P3;
  __shared__ __align__(16) float As[16][68];
  __shared__ __align__(16) float Bs[16][68];
  const int bk = blockIdx.x, bj = blockIdx.y;
  const int tid = threadIdx.x;
  const int tx = tid & 15, ty = tid >> 4;
  const int j0 = bj * 64, k0 = bk * 64;
  float acc[4][4] = {};
  for (int m0 = 0; m0 < 512; m0 += 16) {
#pragma unroll
    for (int l = 0; l < 4; ++l) {
      int lin = tid + 256 * l;
      int mm = lin >> 6, jr = lin & 63;
      As[mm][jr] = P[(m0 + mm) * 512 + j0 + jr];
      int kk = lin >> 4, mb = lin & 15;
      Bs[mb][kk] = W[(k0 + kk) * 512 + m0 + mb] * cosf(rx[m0 + mb]);
    }
    __syncthreads();
#pragma unroll
    for (int mm = 0; mm < 16; ++mm) {
      f32x4 a = *(const f32x4*)&As[mm][ty * 4];
      f32x4 b = *(const f32x4*)&Bs[mm][tx * 4];
#pragma unroll
      for (int i = 0; i < 4; ++i)
#pragma unroll
        for (int jj = 0; jj < 4; ++jj)
          acc[i][jj] += a[i] * b[jj];
    }
    __syncthreads();
  }
#pragma unroll
  for (int i = 0; i < 4; ++i) {
    int j = j0 + ty * 4 + i;
    size_t n = (size_t)(j * 4 + g);
    ushort4 w;
    w.x = f2bf(acc[i][0]); w.y = f2bf(acc[i][1]);
    w.z = f2bf(acc[i][2]); w.w = f2bf(acc[i][3]);
    *(ushort4*)(Wt + n * 1024 + k0 + tx * 4) = w;
  }
}

// bpn[j*4+g]; grid 32 = 4 gates x 8 j-blocks
__global__ __launch_bounds__(256) void fold_bias(
    const float* __restrict__ b0, const float* __restrict__ rx0, const float* __restrict__ P0,
    const float* __restrict__ b1, const float* __restrict__ rx1, const float* __restrict__ P1,
    const float* __restrict__ b2, const float* __restrict__ rx2, const float* __restrict__ P2,
    const float* __restrict__ b3, const float* __restrict__ rx3, const float* __restrict__ P3,
    float* __restrict__ bpn)
{
  const int g = blockIdx.x >> 3, jb = blockIdx.x & 7;
  const float* b  = (g == 0) ? b0  : (g == 1) ? b1  : (g == 2) ? b2  : b3;
  const float* rx = (g == 0) ? rx0 : (g == 1) ? rx1 : (g == 2) ? rx2 : rx3;
  const float* P  = (g == 0) ? P0  : (g == 1) ? P1  : (g == 2) ? P2  : P3;
  __shared__ float bc[512];
  __shared__ float red[4][65];
  const int tid = threadIdx.x;
  bc[tid] = b[tid] * cosf(rx[tid]);
  bc[tid + 256] = b[tid + 256] * cosf(rx[tid + 256]);
  __syncthreads();
  const int jl = tid & 63, msub = tid >> 6;
  const int j = jb * 64 + jl;
  float acc = 0.f;
  for (int m = msub * 128; m < msub * 128 + 128; ++m)
    acc += bc[m] * P[m * 512 + j];
  red[msub][jl] = acc;
  __syncthreads();
  if (msub == 0)
    bpn[j * 4 + g] = red[0][jl] + red[1][jl] + red[2][jl] + red[3][jl];
}

__global__ __launch_bounds__(256) void xcvt_kernel(
    const float* __restrict__ x, u16* __restrict__ xb)
{
  size_t i = (size_t)blockIdx.x * 256 + threadIdx.x;
  f32x4 v = *(const f32x4*)(x + i * 4);
  ushort4 w;
  w.x = f2bf(v[0]); w.y = f2bf(v[1]); w.z = f2bf(v[2]); w.w = f2bf(v[3]);
  *(ushort4*)(xb + i * 4) = w;
}

// zero hbuf (both parities) + cbuf + flags, every launch (replay determinism)
__global__ __launch_bounds__(256) void init_kernel(u32* hbuf32, float* cbuf,
                                                   u32* flags) {
  int i = blockIdx.x * 256 + threadIdx.x;      // 65536
  hbuf32[i] = 0;
  cbuf[i] = 0.f;
  if (i < 256) flags[i] = 0;
}

__global__ __launch_bounds__(256) void tail_kernel(
    const float* __restrict__ hlast, const float* __restrict__ c,
    float* __restrict__ hx, float* __restrict__ cx)
{
  int i = blockIdx.x * 256 + threadIdx.x;
  hx[i] = hlast[i];
  cx[i] = c[i];
}

// ---------------------------------------------------------------------------
// fallback single-step kernel (R1-proven)
// ---------------------------------------------------------------------------
__global__ __launch_bounds__(256) void step_kernel(
    const u16* __restrict__ xb_t, const u16* __restrict__ h_in,
    u16* __restrict__ h_out, const u16* __restrict__ Wt,
    const float* __restrict__ bpn, float* __restrict__ cbuf,
    float* __restrict__ out_t)
{
  __shared__ float pre_s[32][33];
  const int bid = blockIdx.x;
  const int mb = bid >> 6, nb = bid & 63;
  const int b0 = mb * 32, n0 = nb * 32;
  const int tid = threadIdx.x;
  const int wv = tid >> 6, lane = tid & 63;
  const int rt = wv >> 1, nt = wv & 1;
  const int l15 = lane & 15, kg = lane >> 4;
  const int brow = b0 + rt * 16 + l15;
  const int ncol = n0 + nt * 16 + l15;
  const u16* wrow = Wt + (size_t)ncol * 1024;
  const u16* xrow = xb_t + (size_t)brow * 512;
  const u16* hrow = h_in + (size_t)brow * 512;
  f32x4 acc = {0.f, 0.f, 0.f, 0.f};
#pragma unroll 8
  for (int kk = 0; kk < 32; ++kk) {
    const int kb = kk * 32 + kg * 8;
    bf16x8 bfrag = *(const bf16x8*)(wrow + kb);
    bf16x8 afrag;
    if (kb < 512) afrag = *(const bf16x8*)(xrow + kb);
    else          afrag = *(const bf16x8*)(hrow + (kb - 512));
    acc = __builtin_amdgcn_mfma_f32_16x16x32_bf16(afrag, bfrag, acc, 0, 0, 0);
  }
  const float bias = bpn[ncol];
#pragma unroll
  for (int q = 0; q < 4; ++q)
    pre_s[rt * 16 + kg * 4 + q][nt * 16 + l15] = acc[q] + bias;
  __syncthreads();
  const int bb = tid >> 3, jo = tid & 7;
  float pf = pre_s[bb][jo * 4 + 0];
  float pi = pre_s[bb][jo * 4 + 1];
  float pu = pre_s[bb][jo * 4 + 2];
  float po = pre_s[bb][jo * 4 + 3];
  float fg = 1.f / (1.f + __expf(-pf));
  float ig = 1.f / (1.f + __expf(-pi));
  float gg = tanhf(pu);
  float og = 1.f / (1.f + __expf(-po));
  size_t idx = (size_t)(b0 + bb) * 512 + (size_t)(nb * 8 + jo);
  float cv = fg * cbuf[idx] + ig * gg;
  cbuf[idx] = cv;
  float hv = og * tanhf(cv);
  out_t[idx] = hv;
  h_out[idx] = f2bf(hv);
}

// ---------------------------------------------------------------------------
// persistent recurrence v14 = R18 minus barriers A and B:
//  - all 4 waves poll the 64 group flags (1/lane, tracked atomic, busy spin)
//    and self-release (no barrier A);
//  - each wave's 16x16 tile = 16 rows x (4 h-cols x 4 gates) -> gate
//    transpose + cell update are INTRA-WAVE (per-wave LDS patch, lgkmcnt
//    only; layout verified by R19's passing absmax) — no barrier B;
//  - barrier C kept (per-step wg re-sync; R19 proved dropping it drifts),
//    release via untracked atomic swap drained wave0-locally.
// ---------------------------------------------------------------------------
__global__ __launch_bounds__(256, 1) void qlstm_persistent(
    const u16* __restrict__ Xbf,    // [256][128][512] bf16
    u16* __restrict__ hbuf,         // [2][128][512] bf16
    const u16* __restrict__ Wt,     // [2048][1024] bf16, n = j*4+g
    const float* __restrict__ bpn,  // [2048] f32
    float* __restrict__ out,        // [256][128][512] + hx + cx
    u32* __restrict__ flags)        // [256]
{
  __shared__ float pre_s[4][16][17];
  const int bid = blockIdx.x;
  const int mb = bid >> 6, nb = bid & 63;
  const int b0 = mb * 32, n0 = nb * 32;
  const int tid = threadIdx.x;
  const int wv = tid >> 6, lane = tid & 63;
  const int rt = wv >> 1, nt = wv & 1;
  const int l15 = lane & 15, kg = lane >> 4;
  const int brow = b0 + rt * 16 + l15;          // A-frag row == cell row
  const int ncol = n0 + nt * 16 + l15;          // B-frag gate col

  // both W halves register-resident (128 VGPR)
  const u16* wrow = Wt + (size_t)ncol * 1024;
  bf16x8 warr[32];
#pragma unroll
  for (int kk = 0; kk < 32; ++kk)
    warr[kk] = *(const bf16x8*)(wrow + kk * 32 + kg * 8);
  const float bnc = bpn[ncol];

  // intra-wave cell mapping: lane owns (row = brow, h-col = jbase + kg)
  const int jbase = nb * 8 + nt * 4;
  const size_t eidx = (size_t)brow * 512 + (size_t)(jbase + kg);
  const size_t hrow_off = (size_t)brow * 512 + (size_t)jbase;
  float cst = 0.f, hl = 0.f;

  // prologue: x-loads for t=0, drained once
  bf16x8 xf[16];
  {
    const u16* xr = Xbf + (size_t)brow * 512;
#pragma unroll
    for (int kk = 0; kk < 16; ++kk)
      ld_g_b128(xr + kk * 32 + kg * 8, xf[kk]);
    asm volatile("s_waitcnt vmcnt(0)" ::: "memory");
  }

  for (int t = 0; t < 256; ++t) {
    // ---- per-wave poll: each of 4 waves checks all 64 group flags ----
    if (t > 0) {
      int guard = 0;
      for (;;) {
        u32 fv = __hip_atomic_load(&flags[mb * 64 + lane], __ATOMIC_RELAXED,
                                   __HIP_MEMORY_SCOPE_AGENT);
        if (__all((int)(fv >= (u32)t))) break;
        if (++guard > 500000) break;           // bounded: fail loudly, no hang
      }
      asm volatile("" ::: "memory");
    }

    // ---- issue coherent h-loads (x landed: drained by poll / prologue) ----
    bf16x8 hf[16];
    if (t > 0) {
      const u16* hr = hbuf + (size_t)((t & 1) ? 65536 : 0) + (size_t)brow * 512;
#pragma unroll
      for (int kk = 0; kk < 16; ++kk)
        ld_llc_b128(hr + kk * 32 + kg * 8, hf[kk]);
    }

    // ---- x-MFMAs from registers ----
    f32x4 ax0 = {0,0,0,0}, ax1 = {0,0,0,0};
#pragma unroll
    for (int kk = 0; kk < 16; kk += 2) {
      ax0 = __builtin_amdgcn_mfma_f32_16x16x32_bf16(xf[kk],     warr[kk],     ax0, 0, 0, 0);
      ax1 = __builtin_amdgcn_mfma_f32_16x16x32_bf16(xf[kk + 1], warr[kk + 1], ax1, 0, 0, 0);
    }

    // ---- h-MFMAs after drain ----
    f32x4 ah0 = {0,0,0,0}, ah1 = {0,0,0,0};
    if (t > 0) {
      asm volatile("s_waitcnt vmcnt(0)" ::: "memory");
      __builtin_amdgcn_sched_barrier(0);
#pragma unroll
      for (int kk = 0; kk < 16; kk += 2) {
        ah0 = __builtin_amdgcn_mfma_f32_16x16x32_bf16(hf[kk],     warr[16 + kk],     ah0, 0, 0, 0);
        ah1 = __builtin_amdgcn_mfma_f32_16x16x32_bf16(hf[kk + 1], warr[16 + kk + 1], ah1, 0, 0, 0);
      }
    }
    f32x4 acc = (ax0 + ax1) + (ah0 + ah1);

    // ---- INTRA-WAVE gate transpose (own LDS patch; lgkmcnt only) ----
    // C/D layout: tile-col = l15, tile-row = kg*4+q
#pragma unroll
    for (int q = 0; q < 4; ++q)
      pre_s[wv][kg * 4 + q][l15] = acc[q] + bnc;
    asm volatile("s_waitcnt lgkmcnt(0)" ::: "memory");
    __builtin_amdgcn_sched_barrier(0);
    f32x4 g4 = *(const f32x4*)&pre_s[wv][l15][kg * 4];
    asm volatile("s_waitcnt lgkmcnt(0)" ::: "memory");
    __builtin_amdgcn_sched_barrier(0);

    // ---- gates + cell update: lane owns (row=brow, col=jbase+kg) ----
    cst = sigm_fast(g4[0]) * cst + sigm_fast(g4[1]) * tanh_fast(g4[2]);
    float hv = sigm_fast(g4[3]) * tanh_fast(cst);
    hl = hv;

    // ---- packed coherent h-store: 4 cols of this row -> one dwordx2 ----
    u16 myh = f2bf(hv);
    u32 w  = (u32)myh | ((u32)(u16)__shfl_xor((int)(u32)myh, 16) << 16);
    u32 w2 = (u32)__shfl_xor((int)w, 32);
    u16* hnext = hbuf + (size_t)(((t + 1) & 1) ? 65536 : 0);
    if (kg == 0) {
      u32x2 hw = {w, w2};
      st_llc_b64(hnext + hrow_off, hw);
    }
    asm volatile("s_waitcnt vmcnt(0)" ::: "memory");   // h-store drained
    __builtin_amdgcn_s_barrier();              // C: the one per-step re-sync
    asm volatile("" ::: "memory");
    if (wv == 0) {
      if (lane == 0)
        at_swap(&flags[bid], (u32)(t + 1));
      asm volatile("s_waitcnt vmcnt(0)" ::: "memory"); // wave0 drains the swap
    }

    // ---- post-flag: out-store + x prefetch for t+1 (fire-and-forget) ----
    union { float f; u32 u; } ho; ho.f = hv;
    st_g_b32((u32*)(out + (size_t)t * 65536 + eidx), ho.u);
    if (t < 255) {
      const u16* xr = Xbf + (size_t)(t + 1) * 65536 + (size_t)brow * 512;
#pragma unroll
      for (int kk = 0; kk < 16; ++kk)
        ld_g_b128(xr + kk * 32 + kg * 8, xf[kk]);
    }
  }

  asm volatile("s_waitcnt vmcnt(0)" ::: "memory");
  out[(size_t)256 * 65536 + eidx] = hl;
  out[(size_t)256 * 65536 + 65536 + eidx] = cst;
}

// ---------------------------------------------------------------------------
extern "C" void kernel_launch(void* const* d_in, const int* in_sizes, int n_in,
                              void* d_out, int out_size, void* d_ws, size_t ws_size,
                              hipStream_t stream) {
  (void)in_sizes; (void)n_in; (void)out_size; (void)ws_size;
  const float* inp = (const float*)d_in[0];
  float* out = (float*)d_out;

  // ws: Xbf 33554432 | Wt 4194304 | bpn 8192 | hbuf 262144 | flags 1024 | cbuf 262144
  char* base = (char*)d_ws;
  u16*   Xbf   = (u16*)base;
  u16*   Wt    = (u16*)(base + 33554432);
  float* bpn   = (float*)(base + 33554432 + 4194304);
  u16*   hbuf  = (u16*)(base + 33554432 + 4194304 + 8192);
  u32*   flags = (u32*)(base + 33554432 + 4194304 + 8192 + 262144);
  float* cbuf  = (float*)(base + 33554432 + 4194304 + 8192 + 262144 + 1024);

  const float* W[4];  const float* b[4];  const float* rx[4];  const float* P[4];
  for (int g = 0; g < 4; ++g) {
    W[g]  = (const float*)d_in[1 + 4 * g];
    b[g]  = (const float*)d_in[2 + 4 * g];
    rx[g] = (const float*)d_in[3 + 4 * g];
    P[g]  = (const float*)d_in[4 + 4 * g];
  }
  fold_kernel<<<dim3(16, 8, 4), 256, 0, stream>>>(
      W[0], rx[0], P[0], W[1], rx[1], P[1],
      W[2], rx[2], P[2], W[3], rx[3], P[3], Wt);
  fold_bias<<<dim3(32), 256, 0, stream>>>(
      b[0], rx[0], P[0], b[1], rx[1], P[1],
      b[2], rx[2], P[2], b[3], rx[3], P[3], bpn);
  xcvt_kernel<<<16384, 256, 0, stream>>>(inp, Xbf);
  init_kernel<<<256, 256, 0, stream>>>((u32*)hbuf, cbuf, flags);

  void* args[6];
  const u16* Xbf_c = Xbf;
  const u16* Wt_c = Wt;
  const float* bpn_c = bpn;
  u16* hbuf_p = hbuf;
  float* out_p = out;
  u32* flags_p = flags;
  args[0] = (void*)&Xbf_c;
  args[1] = (void*)&hbuf_p;
  args[2] = (void*)&Wt_c;
  args[3] = (void*)&bpn_c;
  args[4] = (void*)&out_p;
  args[5] = (void*)&flags_p;
  hipError_t e = hipLaunchCooperativeKernel((const void*)qlstm_persistent,
                                            dim3(256), dim3(256), args, 0, stream);
  if (e != hipSuccess) {
    for (int t = 0; t < 256; ++t) {
      const u16* xb_t  = Xbf + (size_t)t * 65536;
      const u16* h_in  = hbuf + (size_t)(t & 1) * 65536;
      u16*       h_oup = hbuf + (size_t)((t & 1) ^ 1) * 65536;
      float*     out_t = out + (size_t)t * 65536;
      step_kernel<<<256, 256, 0, stream>>>(xb_t, h_in, h_oup, Wt, bpn, cbuf, out_t);
    }
    tail_kernel<<<256, 256, 0, stream>>>(out + (size_t)255 * 65536, cbuf,
                                         out + (size_t)256 * 65536,
                                         out + (size_t)256 * 65536 + 65536);
  }
}